// Round 14
// baseline (363.214 us; speedup 1.0000x reference)
//
#include <hip/hip_runtime.h>

#define NN 100000
#define NE 1600000
#define BSH 7                 // log2(nodes per bucket)
#define BSZ 128               // nodes per bucket
#define NBKT 782              // ceil(NN/BSZ)
#define CAP 2560              // padded slots per bucket
#define NPB 256               // partition blocks
#define EPB 6250              // edges per partition block (NE/NPB, exact)
#define EPW 256               // edges per wave in edge-centric agg1 (NE/EPW = 6250 waves)

typedef unsigned short u16;
typedef unsigned int   u32;
typedef unsigned long long u64;
typedef __attribute__((ext_vector_type(8))) __bf16 bf16x8;
typedef __attribute__((ext_vector_type(4))) float  f32x4;

__device__ __forceinline__ float bf2f(u16 u) {
    union { u32 i; float f; } v; v.i = ((u32)u) << 16; return v.f;
}
__device__ __forceinline__ u16 f2bf(float f) {
    union { float f; u32 i; } v; v.f = f;
    u32 u = v.i;
    u += 0x7FFFu + ((u >> 16) & 1);   // round-to-nearest-even
    return (u16)(u >> 16);
}
__device__ __forceinline__ float bfLO(u32 p) { return __uint_as_float(p << 16); }
__device__ __forceinline__ float bfHI(u32 p) { return __uint_as_float(p & 0xffff0000u); }
__device__ __forceinline__ u64 nt_load_u64(const uint2* p) {
    return __builtin_nontemporal_load((const u64*)p);
}

// ---------------- pack W1/W2 into MFMA B-frag order; init cursors ----------------
__global__ __launch_bounds__(256) void k_wpack(const float* __restrict__ W1,
                                               const float* __restrict__ W2,
                                               bf16x8* __restrict__ wp1,
                                               bf16x8* __restrict__ wp2,
                                               int* __restrict__ cursor,
                                               int* __restrict__ gctr) {
    int t = threadIdx.x;
    #pragma unroll
    for (int s = 0; s < 4; ++s) {
        int idx = s * 256 + t;          // 0..1023
        int q = idx >> 6, l = idx & 63;
        int kb = q >> 2, ct = q & 3;
        int k0 = kb * 32 + ((l >> 4) * 8);
        int c  = ct * 16 + (l & 15);
        bf16x8 v;
        #pragma unroll
        for (int i = 0; i < 8; ++i) v[i] = (__bf16)W1[(k0 + i) * 64 + c];
        wp1[idx] = v;
    }
    if (t < 128) {
        int q = t >> 6, l = t & 63;
        int k0 = q * 32 + ((l >> 4) * 8);
        int c  = l & 15;
        bf16x8 v;
        #pragma unroll
        for (int i = 0; i < 8; ++i) v[i] = (__bf16)W2[(k0 + i) * 16 + c];
        wp2[t] = v;
    }
    for (int i = t; i < NBKT; i += 256) cursor[i] = i * CAP;   // padded bucket bases
    if (t == 0) *gctr = 0;
}

// ---------------- partition: LDS counting-sort per block, coalesced segment writes ----------------
__global__ __launch_bounds__(1024) void k_part(const int* __restrict__ src,
                                               const int* __restrict__ dst,
                                               const float* __restrict__ w,
                                               int* __restrict__ cursor,
                                               uint2* __restrict__ rec) {
    __shared__ uint2 sedge[EPB];      // 50.0 KB
    __shared__ u16   sbkt[EPB];       // 12.5 KB
    __shared__ int   cnt[NBKT];
    __shared__ int   lstart[NBKT];
    __shared__ int   gbase[NBKT];
    __shared__ int   scanbuf[1024];
    int tid = threadIdx.x;
    int e0  = blockIdx.x * EPB;

    for (int i = tid; i < NBKT; i += 1024) cnt[i] = 0;
    __syncthreads();
    for (int j = tid; j < EPB; j += 1024)
        atomicAdd(&cnt[dst[e0 + j] >> BSH], 1);
    __syncthreads();
    int v = (tid < NBKT) ? cnt[tid] : 0;
    scanbuf[tid] = v;
    __syncthreads();
    #pragma unroll
    for (int off = 1; off < 1024; off <<= 1) {
        int add = (tid >= off) ? scanbuf[tid - off] : 0;
        __syncthreads();
        scanbuf[tid] += add;
        __syncthreads();
    }
    if (tid < NBKT) lstart[tid] = scanbuf[tid] - v;
    __syncthreads();
    for (int i = tid; i < NBKT; i += 1024) {
        int c = cnt[i];
        gbase[i] = c ? atomicAdd(&cursor[i], c) : 0;
        cnt[i] = 0;
    }
    __syncthreads();
    for (int j = tid; j < EPB; j += 1024) {
        int e  = e0 + j;
        int d  = dst[e];
        int bk = d >> BSH;
        int slot = lstart[bk] + atomicAdd(&cnt[bk], 1);
        sedge[slot] = make_uint2(__float_as_uint(w[e]),
                                 ((u32)src[e] << BSH) | (u32)(d & (BSZ - 1)));
        sbkt[slot]  = (u16)bk;
    }
    __syncthreads();
    for (int j = tid; j < EPB; j += 1024) {
        int bk   = sbkt[j];
        int dest = gbase[bk] + (j - lstart[bk]);
        rec[dest] = sedge[j];
    }
}

// ---------------- per-bucket: deg -> dis, counting-sort to dense per-node CSR ----------------
__global__ __launch_bounds__(512) void k_build(const int* __restrict__ cursor,
                                               const uint2* __restrict__ rec,
                                               uint2* __restrict__ rec2,
                                               u32*  __restrict__ dste,
                                               float* __restrict__ dis,
                                               int2* __restrict__ rowinfo,
                                               int* __restrict__ gctr) {
    __shared__ float dw[BSZ];
    __shared__ int   cnt[BSZ];
    __shared__ int   base[BSZ];
    __shared__ int   scn[BSZ];
    __shared__ float disl[BSZ];
    __shared__ int   sh_gbase;
    int b = blockIdx.x, tid = threadIdx.x;
    int s = b * CAP;
    int total = cursor[b] - s;
    if (tid < BSZ) { dw[tid] = 1.0f; cnt[tid] = 0; }
    if (tid == 0) sh_gbase = atomicAdd(gctr, total);
    __syncthreads();
    for (int j = tid; j < total; j += 512) {
        uint2 r = rec[s + j];
        int dl = r.y & (BSZ - 1);
        atomicAdd(&cnt[dl], 1);
        atomicAdd(&dw[dl], __uint_as_float(r.x));
    }
    __syncthreads();
    if (tid < BSZ) scn[tid] = cnt[tid];
    __syncthreads();
    #pragma unroll
    for (int off = 1; off < BSZ; off <<= 1) {
        int add = (tid < BSZ && tid >= off) ? scn[tid - off] : 0;
        __syncthreads();
        if (tid < BSZ) scn[tid] += add;
        __syncthreads();
    }
    int gbase = sh_gbase;
    if (tid < BSZ) {
        int node = b * BSZ + tid;
        base[tid] = (tid == 0) ? 0 : scn[tid - 1];
        float d = rsqrtf(dw[tid]);
        disl[tid] = d;
        if (node < NN) {
            dis[node] = d;
            rowinfo[node] = make_int2(gbase + base[tid], gbase + base[tid] + cnt[tid]);
        }
        cnt[tid] = 0;
    }
    __syncthreads();
    for (int j = tid; j < total; j += 512) {
        uint2 r = rec[s + j];
        int dl = r.y & (BSZ - 1);
        int pos = gbase + base[dl] + atomicAdd(&cnt[dl], 1);
        rec2[pos] = make_uint2(__float_as_uint(__uint_as_float(r.x) * disl[dl]),
                               r.y >> BSH);
        dste[pos] = (u32)(b * BSZ + dl);
    }
}

// ---------------- h1b = bf16(dis * (x @ W1)) via MFMA ----------------
__global__ __launch_bounds__(256) void k_gemm1(const float* __restrict__ x,
                                               const bf16x8* __restrict__ wp1,
                                               const float* __restrict__ dis,
                                               u16* __restrict__ h1b) {
    int tid  = threadIdx.x;
    int lane = tid & 63;
    int wave = tid >> 6;
    int r0   = blockIdx.x * 64 + wave * 16;

    bf16x8 bfrag[16];
    #pragma unroll
    for (int q = 0; q < 16; ++q) bfrag[q] = wp1[q * 64 + lane];

    int  arow = r0 + (lane & 15);
    bool aok  = arow < NN;
    const float* xrow = x + (size_t)arow * 128 + ((lane >> 4) * 8);

    f32x4 acc0 = {0,0,0,0}, acc1 = {0,0,0,0}, acc2 = {0,0,0,0}, acc3 = {0,0,0,0};
    #pragma unroll
    for (int kb = 0; kb < 4; ++kb) {
        f32x4 xlo = {0,0,0,0}, xhi = {0,0,0,0};
        if (aok) {
            xlo = *(const f32x4*)(xrow + kb * 32);
            xhi = *(const f32x4*)(xrow + kb * 32 + 4);
        }
        bf16x8 a;
        a[0] = (__bf16)xlo[0]; a[1] = (__bf16)xlo[1]; a[2] = (__bf16)xlo[2]; a[3] = (__bf16)xlo[3];
        a[4] = (__bf16)xhi[0]; a[5] = (__bf16)xhi[1]; a[6] = (__bf16)xhi[2]; a[7] = (__bf16)xhi[3];
        acc0 = __builtin_amdgcn_mfma_f32_16x16x32_bf16(a, bfrag[kb * 4 + 0], acc0, 0, 0, 0);
        acc1 = __builtin_amdgcn_mfma_f32_16x16x32_bf16(a, bfrag[kb * 4 + 1], acc1, 0, 0, 0);
        acc2 = __builtin_amdgcn_mfma_f32_16x16x32_bf16(a, bfrag[kb * 4 + 2], acc2, 0, 0, 0);
        acc3 = __builtin_amdgcn_mfma_f32_16x16x32_bf16(a, bfrag[kb * 4 + 3], acc3, 0, 0, 0);
    }

    int rbase = r0 + (lane >> 4) * 4;
    int cbase = lane & 15;
    #pragma unroll
    for (int reg = 0; reg < 4; ++reg) {
        int row = rbase + reg;
        if (row < NN) {
            float d = dis[row];
            u16* hp = h1b + (size_t)row * 64 + cbase;
            hp[0]  = f2bf(acc0[reg] * d);
            hp[16] = f2bf(acc1[reg] * d);
            hp[32] = f2bf(acc2[reg] * d);
            hp[48] = f2bf(acc3[reg] * d);
        }
    }
}

// ---------------- deg-0 nodes: write init row (xemb pre-zeroed) ----------------
__global__ __launch_bounds__(256) void k_fix0(const int2* __restrict__ rowinfo,
                                              const u16* __restrict__ h1b,
                                              const float* __restrict__ dis,
                                              const float* __restrict__ b1,
                                              float* __restrict__ xemb) {
    int n = (blockIdx.x * 256 + threadIdx.x) >> 6;
    int f = threadIdx.x & 63;
    int2 ri = rowinfo[n];
    if (ri.x == ri.y)
        xemb[(size_t)n * 64 + f] = fmaf(dis[n], bf2f(h1b[(size_t)n * 64 + f]), b1[f]);
}

// ---------------- layer-1 aggregation: EDGE-CENTRIC segmented reduction ----------------
// wave = 256-edge range of dst-sorted rec2; lane = feature. 8 gathers in flight
// (raw u16 staged, converted at consume). Flush on dst change: direct store w/ init,
// atomicAdd for range-boundary nodes (xemb pre-zeroed).
__global__ __launch_bounds__(512) void k_agge1(const uint2* __restrict__ rec2,
                                               const u32* __restrict__ dste,
                                               const u16* __restrict__ h1b,
                                               const float* __restrict__ dis,
                                               const float* __restrict__ b1,
                                               float* __restrict__ xemb) {
    int wid = blockIdx.x * 8 + (threadIdx.x >> 6);
    if (wid >= NE / EPW) return;
    int f  = threadIdx.x & 63;
    int jb = wid * EPW, je = jb + EPW;          // NE % EPW == 0
    int pd = (jb > 0)  ? (int)dste[jb - 1] : -1;
    int nd = (je < NE) ? (int)dste[je]     : -1;
    float bf_ = b1[f];

    u64   ru[8];    // rec2 staged for j+8..j+15
    float pn[8];    // norm for j..j+7
    u16   pv[8];    // gathered h1b (raw) for j..j+7
    int   dn[8];    // dst for j..j+7
    #pragma unroll
    for (int k = 0; k < 8; ++k) {
        u64 r = nt_load_u64(&rec2[jb + k]);
        pn[k] = __uint_as_float((u32)r);
        pv[k] = h1b[(size_t)(u32)(r >> 32) * 64 + f];
        dn[k] = (int)dste[jb + k];
        ru[k] = (jb + 8 + k < NE) ? nt_load_u64(&rec2[jb + 8 + k]) : 0;
    }

    int   curn = dn[0];
    bool  firstseg = true;
    float acc = 0.f;

    for (int j = jb; j < je; j += 8) {
        #pragma unroll
        for (int k = 0; k < 8; ++k) {
            int jj = j + k;
            int nn = dn[k];
            if (nn != curn) {   // wave-uniform: flush completed segment
                bool cont_in = firstseg && (curn == pd);
                if (cont_in) {
                    atomicAdd(&xemb[(size_t)curn * 64 + f], acc);
                } else {
                    float init = fmaf(dis[curn], bf2f(h1b[(size_t)curn * 64 + f]), bf_);
                    xemb[(size_t)curn * 64 + f] = acc + init;
                }
                firstseg = false;
                curn = nn; acc = 0.f;
            }
            acc = fmaf(pn[k], bf2f(pv[k]), acc);
            int j8 = jj + 8;
            if (j8 < je) {      // refill slot k
                u64 r = ru[k];
                pn[k] = __uint_as_float((u32)r);
                pv[k] = h1b[(size_t)(u32)(r >> 32) * 64 + f];
                dn[k] = (int)dste[j8];
                ru[k] = (jj + 16 < NE) ? nt_load_u64(&rec2[jj + 16]) : 0;
            }
        }
    }
    // final segment: may continue into previous/next range
    bool cont_in  = firstseg && (curn == pd);
    bool cont_out = (curn == nd);
    if (cont_in || cont_out) {
        float init = cont_in ? 0.f
                   : fmaf(dis[curn], bf2f(h1b[(size_t)curn * 64 + f]), bf_);
        atomicAdd(&xemb[(size_t)curn * 64 + f], acc + init);
    } else {
        float init = fmaf(dis[curn], bf2f(h1b[(size_t)curn * 64 + f]), bf_);
        xemb[(size_t)curn * 64 + f] = acc + init;
    }
}

// ---------------- h3b = bf16(dis * (relu(xemb) @ W2)) via MFMA ----------------
__global__ __launch_bounds__(256) void k_gemm2(const float* __restrict__ xemb,
                                               const bf16x8* __restrict__ wp2,
                                               const float* __restrict__ dis,
                                               u16* __restrict__ h3b) {
    int tid  = threadIdx.x;
    int lane = tid & 63;
    int wave = tid >> 6;
    int r0   = blockIdx.x * 64 + wave * 16;

    bf16x8 b0 = wp2[lane], b1 = wp2[64 + lane];

    int  arow = r0 + (lane & 15);
    bool aok  = arow < NN;
    const float* xrow = xemb + (size_t)arow * 64 + ((lane >> 4) * 8);

    f32x4 acc = {0,0,0,0};
    #pragma unroll
    for (int kb = 0; kb < 2; ++kb) {
        f32x4 xlo = {0,0,0,0}, xhi = {0,0,0,0};
        if (aok) {
            xlo = *(const f32x4*)(xrow + kb * 32);
            xhi = *(const f32x4*)(xrow + kb * 32 + 4);
        }
        bf16x8 a;
        #pragma unroll
        for (int i = 0; i < 4; ++i) {
            float lo = xlo[i] > 0.f ? xlo[i] : 0.f;   // fused ReLU
            float hi = xhi[i] > 0.f ? xhi[i] : 0.f;
            a[i]     = (__bf16)lo;
            a[i + 4] = (__bf16)hi;
        }
        acc = __builtin_amdgcn_mfma_f32_16x16x32_bf16(a, kb == 0 ? b0 : b1, acc, 0, 0, 0);
    }

    int rbase = r0 + (lane >> 4) * 4;
    int cbase = lane & 15;
    #pragma unroll
    for (int reg = 0; reg < 4; ++reg) {
        int row = rbase + reg;
        if (row < NN)
            h3b[(size_t)row * 16 + cbase] = f2bf(acc[reg] * dis[row]);
    }
}

// ---------------- layer-2 aggregation: wave = node (unchanged) ----------------
__global__ __launch_bounds__(512) void k_agg2(const int2* __restrict__ rowinfo,
                                              const uint2* __restrict__ rec2,
                                              const u16* __restrict__ h3b,
                                              const float* __restrict__ dis,
                                              const float* __restrict__ b2,
                                              float* __restrict__ out) {
    int n    = blockIdx.x * 8 + (threadIdx.x >> 6);
    int lane = threadIdx.x & 63;
    int el   = lane >> 2;
    int f4   = (lane & 3) * 4;
    int2 ri  = rowinfo[n];
    int beg = ri.x, end = ri.y;

    float a0=0,a1=0,a2=0,a3=0;

    u64 p0 = 0, p1 = 0;
    if (beg + el < end)      p0 = nt_load_u64(&rec2[beg + el]);
    if (beg + 16 + el < end) p1 = nt_load_u64(&rec2[beg + 16 + el]);

    for (int j = beg; j < end; j += 32) {
        u64 q0 = 0, q1 = 0;
        if (j + 32 + el < end) q0 = nt_load_u64(&rec2[j + 32 + el]);
        if (j + 48 + el < end) q1 = nt_load_u64(&rec2[j + 48 + el]);
        if (j + el < end) {
            u32 srcn = (u32)(p0 >> 32);
            float nrm = __uint_as_float((u32)p0);
            uint2 hv = *(const uint2*)(h3b + (size_t)srcn * 16 + f4);
            a0 = fmaf(nrm, bfLO(hv.x), a0); a1 = fmaf(nrm, bfHI(hv.x), a1);
            a2 = fmaf(nrm, bfLO(hv.y), a2); a3 = fmaf(nrm, bfHI(hv.y), a3);
        }
        if (j + 16 + el < end) {
            u32 srcn = (u32)(p1 >> 32);
            float nrm = __uint_as_float((u32)p1);
            uint2 hv = *(const uint2*)(h3b + (size_t)srcn * 16 + f4);
            a0 = fmaf(nrm, bfLO(hv.x), a0); a1 = fmaf(nrm, bfHI(hv.x), a1);
            a2 = fmaf(nrm, bfLO(hv.y), a2); a3 = fmaf(nrm, bfHI(hv.y), a3);
        }
        p0 = q0; p1 = q1;
    }

    #pragma unroll
    for (int m = 4; m <= 32; m <<= 1) {
        a0 += __shfl_xor(a0, m, 64);
        a1 += __shfl_xor(a1, m, 64);
        a2 += __shfl_xor(a2, m, 64);
        a3 += __shfl_xor(a3, m, 64);
    }
    if (lane < 4) {
        float di = dis[n];
        uint2 hv = *(const uint2*)(h3b + (size_t)n * 16 + f4);
        float4 bb = *(const float4*)&b2[f4];
        float4 r;
        r.x = fmaf(di, bfLO(hv.x), bb.x) + a0;
        r.y = fmaf(di, bfHI(hv.x), bb.y) + a1;
        r.z = fmaf(di, bfLO(hv.y), bb.z) + a2;
        r.w = fmaf(di, bfHI(hv.y), bb.w) + a3;
        *(float4*)&out[(size_t)n * 16 + f4] = r;
    }
}

extern "C" void kernel_launch(void* const* d_in, const int* in_sizes, int n_in,
                              void* d_out, int out_size, void* d_ws, size_t ws_size,
                              hipStream_t stream) {
    const float* x  = (const float*)d_in[0];
    const int*   ei = (const int*)d_in[1];
    const float* w  = (const float*)d_in[2];
    const float* W1 = (const float*)d_in[3];
    const float* b1 = (const float*)d_in[4];
    const float* W2 = (const float*)d_in[5];
    const float* b2 = (const float*)d_in[6];
    const int* src = ei;
    const int* dst = ei + NE;

    float* out2 = (float*)d_out;               // [NN,16]  output 0
    float* xemb = (float*)d_out + NN * 16;     // [NN,64]  output 1

    // workspace (~40 MB): h1b ALIASES rec_pad (rec dead after k_build)
    uint2*  rec_pad = (uint2*)d_ws;                      // NBKT*CAP uint2 = 16.0MB
    u16*    h1b     = (u16*)d_ws;                        // NN*64 u16 = 12.8MB (alias)
    uint2*  rec2    = rec_pad + (size_t)NBKT * CAP;      // NE uint2 = 12.8MB
    u32*    dste    = (u32*)(rec2 + NE);                 // NE u32 = 6.4MB
    u16*    h3b     = (u16*)(dste + NE);                 // NN*16 u16 = 3.2MB
    bf16x8* wp1     = (bf16x8*)(h3b + (size_t)NN * 16);  // 16KB
    bf16x8* wp2     = wp1 + 1024;                        // 2KB
    float*  dis     = (float*)(wp2 + 128);               // NN
    int2*   rowinfo = (int2*)(dis + NN);                 // NN int2
    int*    cursor  = (int*)(rowinfo + NN);              // NBKT
    int*    gctr    = cursor + NBKT;                     // 1

    // --- build (shared by both layers) ---
    k_wpack<<<1,     256, 0, stream>>>(W1, W2, wp1, wp2, cursor, gctr);
    k_part <<<NPB,  1024, 0, stream>>>(src, dst, w, cursor, rec_pad);
    k_build<<<NBKT,  512, 0, stream>>>(cursor, rec_pad, rec2, dste, dis, rowinfo, gctr);
    hipMemsetAsync(xemb, 0, (size_t)NN * 64 * sizeof(float), stream);

    // --- layer 1 ---
    k_gemm1<<<(NN + 63) / 64, 256, 0, stream>>>(x, wp1, dis, h1b);
    k_fix0 <<<NN * 64 / 256, 256, 0, stream>>>(rowinfo, h1b, dis, b1, xemb);
    k_agge1<<<(NE / EPW + 7) / 8, 512, 0, stream>>>(rec2, dste, h1b, dis, b1, xemb);

    // --- layer 2 ---
    k_gemm2<<<(NN + 63) / 64, 256, 0, stream>>>(xemb, wp2, dis, h3b);
    k_agg2 <<<NN / 8, 512, 0, stream>>>(rowinfo, rec2, h3b, dis, b2, out2);
}

// Round 15
// 159.028 us; speedup vs baseline: 2.2840x; 2.2840x over previous
//
#include <hip/hip_runtime.h>

#define NN 100000
#define NE 1600000
#define BSH 7                 // log2(nodes per bucket)
#define BSZ 128               // nodes per bucket
#define NBKT 782              // ceil(NN/BSZ)
#define CAP 2560              // padded slots per bucket (mean 2048, sd ~45 -> 11 sigma)
#define NPB 256               // partition blocks
#define EPB 6250              // edges per partition block (NE/NPB, exact)

typedef unsigned short u16;
typedef unsigned int   u32;
typedef unsigned long long u64;
typedef __attribute__((ext_vector_type(8))) __bf16 bf16x8;
typedef __attribute__((ext_vector_type(4))) float  f32x4;

__device__ __forceinline__ float bf2f(u16 u) {
    union { u32 i; float f; } v; v.i = ((u32)u) << 16; return v.f;
}
__device__ __forceinline__ u16 f2bf(float f) {
    union { float f; u32 i; } v; v.f = f;
    u32 u = v.i;
    u += 0x7FFFu + ((u >> 16) & 1);   // round-to-nearest-even
    return (u16)(u >> 16);
}
__device__ __forceinline__ float bfLO(u32 p) { return __uint_as_float(p << 16); }
__device__ __forceinline__ float bfHI(u32 p) { return __uint_as_float(p & 0xffff0000u); }
__device__ __forceinline__ u64 nt_load_u64(const uint2* p) {
    return __builtin_nontemporal_load((const u64*)p);
}

// ---------------- pack W1/W2 into MFMA B-frag order; init cursors ----------------
__global__ __launch_bounds__(256) void k_wpack(const float* __restrict__ W1,
                                               const float* __restrict__ W2,
                                               bf16x8* __restrict__ wp1,
                                               bf16x8* __restrict__ wp2,
                                               int* __restrict__ cursor,
                                               int* __restrict__ gctr) {
    int t = threadIdx.x;
    #pragma unroll
    for (int s = 0; s < 4; ++s) {
        int idx = s * 256 + t;          // 0..1023
        int q = idx >> 6, l = idx & 63;
        int kb = q >> 2, ct = q & 3;
        int k0 = kb * 32 + ((l >> 4) * 8);
        int c  = ct * 16 + (l & 15);
        bf16x8 v;
        #pragma unroll
        for (int i = 0; i < 8; ++i) v[i] = (__bf16)W1[(k0 + i) * 64 + c];
        wp1[idx] = v;
    }
    if (t < 128) {
        int q = t >> 6, l = t & 63;
        int k0 = q * 32 + ((l >> 4) * 8);
        int c  = l & 15;
        bf16x8 v;
        #pragma unroll
        for (int i = 0; i < 8; ++i) v[i] = (__bf16)W2[(k0 + i) * 16 + c];
        wp2[t] = v;
    }
    for (int i = t; i < NBKT; i += 256) cursor[i] = i * CAP;   // padded bucket bases
    if (t == 0) *gctr = 0;
}

// ---------------- partition: LDS counting-sort per block, coalesced segment writes ----------------
__global__ __launch_bounds__(1024) void k_part(const int* __restrict__ src,
                                               const int* __restrict__ dst,
                                               const float* __restrict__ w,
                                               int* __restrict__ cursor,
                                               uint2* __restrict__ rec) {
    __shared__ uint2 sedge[EPB];      // 50.0 KB
    __shared__ u16   sbkt[EPB];       // 12.5 KB
    __shared__ int   cnt[NBKT];
    __shared__ int   lstart[NBKT];
    __shared__ int   gbase[NBKT];
    __shared__ int   scanbuf[1024];
    int tid = threadIdx.x;
    int e0  = blockIdx.x * EPB;

    for (int i = tid; i < NBKT; i += 1024) cnt[i] = 0;
    __syncthreads();
    for (int j = tid; j < EPB; j += 1024)
        atomicAdd(&cnt[dst[e0 + j] >> BSH], 1);
    __syncthreads();
    int v = (tid < NBKT) ? cnt[tid] : 0;
    scanbuf[tid] = v;
    __syncthreads();
    #pragma unroll
    for (int off = 1; off < 1024; off <<= 1) {
        int add = (tid >= off) ? scanbuf[tid - off] : 0;
        __syncthreads();
        scanbuf[tid] += add;
        __syncthreads();
    }
    if (tid < NBKT) lstart[tid] = scanbuf[tid] - v;
    __syncthreads();
    for (int i = tid; i < NBKT; i += 1024) {
        int c = cnt[i];
        gbase[i] = c ? atomicAdd(&cursor[i], c) : 0;
        cnt[i] = 0;
    }
    __syncthreads();
    for (int j = tid; j < EPB; j += 1024) {
        int e  = e0 + j;
        int d  = dst[e];
        int bk = d >> BSH;
        int slot = lstart[bk] + atomicAdd(&cnt[bk], 1);
        sedge[slot] = make_uint2(__float_as_uint(w[e]),
                                 ((u32)src[e] << BSH) | (u32)(d & (BSZ - 1)));
        sbkt[slot]  = (u16)bk;
    }
    __syncthreads();
    for (int j = tid; j < EPB; j += 1024) {
        int bk   = sbkt[j];
        int dest = gbase[bk] + (j - lstart[bk]);
        rec[dest] = sedge[j];
    }
}

// ---------------- per-bucket: deg -> dis, counting-sort to dense per-node CSR ----------------
// LDS-staged: bucket's edges read from global ONCE, scattered from LDS.
__global__ __launch_bounds__(512) void k_build(const int* __restrict__ cursor,
                                               const uint2* __restrict__ rec,
                                               uint2* __restrict__ rec2,
                                               float* __restrict__ dis,
                                               int2* __restrict__ rowinfo,
                                               int* __restrict__ gctr) {
    __shared__ uint2 sedge[CAP];      // 20.5 KB  staged bucket edges
    __shared__ float dw[BSZ];
    __shared__ int   cnt[BSZ];
    __shared__ int   base[BSZ];
    __shared__ int   scn[BSZ];
    __shared__ float disl[BSZ];
    __shared__ int   sh_gbase;
    int b = blockIdx.x, tid = threadIdx.x;
    int s = b * CAP;
    int total = cursor[b] - s;          // edges in this bucket
    if (tid < BSZ) { dw[tid] = 1.0f; cnt[tid] = 0; }   // self-loop weight
    if (tid == 0) sh_gbase = atomicAdd(gctr, total);   // dense reservation
    __syncthreads();
    for (int j = tid; j < total; j += 512) {           // single global read + stage
        uint2 r = rec[s + j];
        sedge[j] = r;
        int dl = r.y & (BSZ - 1);
        atomicAdd(&cnt[dl], 1);
        atomicAdd(&dw[dl], __uint_as_float(r.x));
    }
    __syncthreads();
    if (tid < BSZ) scn[tid] = cnt[tid];
    __syncthreads();
    #pragma unroll
    for (int off = 1; off < BSZ; off <<= 1) {          // Hillis-Steele over 128
        int add = (tid < BSZ && tid >= off) ? scn[tid - off] : 0;
        __syncthreads();
        if (tid < BSZ) scn[tid] += add;
        __syncthreads();
    }
    int gbase = sh_gbase;
    if (tid < BSZ) {
        int node = b * BSZ + tid;
        base[tid] = (tid == 0) ? 0 : scn[tid - 1];
        float d = rsqrtf(dw[tid]);                     // dw >= 1 always
        disl[tid] = d;
        if (node < NN) {
            dis[node] = d;
            rowinfo[node] = make_int2(gbase + base[tid], gbase + base[tid] + cnt[tid]);
        }
        cnt[tid] = 0;                                   // reuse as cursor
    }
    __syncthreads();
    for (int j = tid; j < total; j += 512) {           // scatter from LDS
        uint2 r = sedge[j];
        int dl = r.y & (BSZ - 1);
        int pos = gbase + base[dl] + atomicAdd(&cnt[dl], 1);
        rec2[pos] = make_uint2(__float_as_uint(__uint_as_float(r.x) * disl[dl]),
                               r.y >> BSH);
    }
}

// ---------------- h1b = bf16(dis * (x @ W1)) via MFMA ----------------
__global__ __launch_bounds__(256) void k_gemm1(const float* __restrict__ x,
                                               const bf16x8* __restrict__ wp1,
                                               const float* __restrict__ dis,
                                               u16* __restrict__ h1b) {
    int tid  = threadIdx.x;
    int lane = tid & 63;
    int wave = tid >> 6;
    int r0   = blockIdx.x * 64 + wave * 16;

    bf16x8 bfrag[16];
    #pragma unroll
    for (int q = 0; q < 16; ++q) bfrag[q] = wp1[q * 64 + lane];  // coalesced, L2-hot

    int  arow = r0 + (lane & 15);
    bool aok  = arow < NN;
    const float* xrow = x + (size_t)arow * 128 + ((lane >> 4) * 8);

    f32x4 acc0 = {0,0,0,0}, acc1 = {0,0,0,0}, acc2 = {0,0,0,0}, acc3 = {0,0,0,0};
    #pragma unroll
    for (int kb = 0; kb < 4; ++kb) {
        f32x4 xlo = {0,0,0,0}, xhi = {0,0,0,0};
        if (aok) {
            xlo = *(const f32x4*)(xrow + kb * 32);
            xhi = *(const f32x4*)(xrow + kb * 32 + 4);
        }
        bf16x8 a;
        a[0] = (__bf16)xlo[0]; a[1] = (__bf16)xlo[1]; a[2] = (__bf16)xlo[2]; a[3] = (__bf16)xlo[3];
        a[4] = (__bf16)xhi[0]; a[5] = (__bf16)xhi[1]; a[6] = (__bf16)xhi[2]; a[7] = (__bf16)xhi[3];
        acc0 = __builtin_amdgcn_mfma_f32_16x16x32_bf16(a, bfrag[kb * 4 + 0], acc0, 0, 0, 0);
        acc1 = __builtin_amdgcn_mfma_f32_16x16x32_bf16(a, bfrag[kb * 4 + 1], acc1, 0, 0, 0);
        acc2 = __builtin_amdgcn_mfma_f32_16x16x32_bf16(a, bfrag[kb * 4 + 2], acc2, 0, 0, 0);
        acc3 = __builtin_amdgcn_mfma_f32_16x16x32_bf16(a, bfrag[kb * 4 + 3], acc3, 0, 0, 0);
    }

    int rbase = r0 + (lane >> 4) * 4;
    int cbase = lane & 15;
    #pragma unroll
    for (int reg = 0; reg < 4; ++reg) {
        int row = rbase + reg;
        if (row < NN) {
            float d = dis[row];
            u16* hp = h1b + (size_t)row * 64 + cbase;
            hp[0]  = f2bf(acc0[reg] * d);
            hp[16] = f2bf(acc1[reg] * d);
            hp[32] = f2bf(acc2[reg] * d);
            hp[48] = f2bf(acc3[reg] * d);
        }
    }
}

// ---------------- layer-1 aggregation: 2-stage gather pipeline (proven 52us) ----------------
#define ACC8(hv, nrm) { \
    a0 = fmaf(nrm, bfLO(hv.x), a0); a1 = fmaf(nrm, bfHI(hv.x), a1); \
    a2 = fmaf(nrm, bfLO(hv.y), a2); a3 = fmaf(nrm, bfHI(hv.y), a3); \
    a4 = fmaf(nrm, bfLO(hv.z), a4); a5 = fmaf(nrm, bfHI(hv.z), a5); \
    a6 = fmaf(nrm, bfLO(hv.w), a6); a7 = fmaf(nrm, bfHI(hv.w), a7); }

__global__ __launch_bounds__(512) void k_agg1(const int2* __restrict__ rowinfo,
                                              const uint2* __restrict__ rec2,
                                              const u16* __restrict__ h1b,
                                              const float* __restrict__ dis,
                                              const float* __restrict__ b1,
                                              float* __restrict__ xemb) {
    int n    = blockIdx.x * 8 + (threadIdx.x >> 6);
    int lane = threadIdx.x & 63;
    int el   = lane >> 3;        // edge slot 0..7
    int f8   = (lane & 7) * 8;   // feature window (8 bf16 = 16B)
    int2 ri  = rowinfo[n];
    int beg = ri.x, end = ri.y;

    float a0=0,a1=0,a2=0,a3=0,a4=0,a5=0,a6=0,a7=0;

    int j0 = beg + el;
    u64 r0 = 0, r1 = 0, r2 = 0, r3 = 0;
    if (j0 < end)      r0 = nt_load_u64(&rec2[j0]);
    if (j0 + 8 < end)  r1 = nt_load_u64(&rec2[j0 + 8]);
    if (j0 + 16 < end) r2 = nt_load_u64(&rec2[j0 + 16]);
    if (j0 + 24 < end) r3 = nt_load_u64(&rec2[j0 + 24]);
    uint4 g0 = {0,0,0,0}, g1 = {0,0,0,0};
    float n0 = 0.f, n1 = 0.f;
    if (j0 < end) {
        g0 = *(const uint4*)(h1b + (size_t)(u32)(r0 >> 32) * 64 + f8);
        n0 = __uint_as_float((u32)r0);
    }
    if (j0 + 8 < end) {
        g1 = *(const uint4*)(h1b + (size_t)(u32)(r1 >> 32) * 64 + f8);
        n1 = __uint_as_float((u32)r1);
    }

    for (int j = beg; j < end; j += 16) {
        uint4 h2 = {0,0,0,0}, h3 = {0,0,0,0};
        float n2 = 0.f, n3 = 0.f;
        if (j0 + 16 < end) {
            h2 = *(const uint4*)(h1b + (size_t)(u32)(r2 >> 32) * 64 + f8);
            n2 = __uint_as_float((u32)r2);
        }
        if (j0 + 24 < end) {
            h3 = *(const uint4*)(h1b + (size_t)(u32)(r3 >> 32) * 64 + f8);
            n3 = __uint_as_float((u32)r3);
        }
        u64 nr0 = 0, nr1 = 0;
        if (j0 + 32 < end) nr0 = nt_load_u64(&rec2[j0 + 32]);
        if (j0 + 40 < end) nr1 = nt_load_u64(&rec2[j0 + 40]);
        ACC8(g0, n0);
        ACC8(g1, n1);
        g0 = h2; n0 = n2; g1 = h3; n1 = n3;
        r0 = r2; r1 = r3; r2 = nr0; r3 = nr1;
        j0 += 16;
    }

    #pragma unroll
    for (int m = 8; m <= 32; m <<= 1) {
        a0 += __shfl_xor(a0, m, 64); a1 += __shfl_xor(a1, m, 64);
        a2 += __shfl_xor(a2, m, 64); a3 += __shfl_xor(a3, m, 64);
        a4 += __shfl_xor(a4, m, 64); a5 += __shfl_xor(a5, m, 64);
        a6 += __shfl_xor(a6, m, 64); a7 += __shfl_xor(a7, m, 64);
    }
    if (el == 0) {   // lanes 0..7, each owns 8 features
        float di = dis[n];
        uint4 hv = *(const uint4*)(h1b + (size_t)n * 64 + f8);   // self-loop
        f32x4 lo, hi;
        lo[0] = fmaf(di, bfLO(hv.x), b1[f8 + 0]) + a0;
        lo[1] = fmaf(di, bfHI(hv.x), b1[f8 + 1]) + a1;
        lo[2] = fmaf(di, bfLO(hv.y), b1[f8 + 2]) + a2;
        lo[3] = fmaf(di, bfHI(hv.y), b1[f8 + 3]) + a3;
        hi[0] = fmaf(di, bfLO(hv.z), b1[f8 + 4]) + a4;
        hi[1] = fmaf(di, bfHI(hv.z), b1[f8 + 5]) + a5;
        hi[2] = fmaf(di, bfLO(hv.w), b1[f8 + 6]) + a6;
        hi[3] = fmaf(di, bfHI(hv.w), b1[f8 + 7]) + a7;
        f32x4* dst0 = (f32x4*)&xemb[(size_t)n * 64 + f8];
        __builtin_nontemporal_store(lo, dst0);
        __builtin_nontemporal_store(hi, dst0 + 1);
    }
}

// ---------------- h3b = bf16(dis * (relu(xemb) @ W2)) via MFMA ----------------
__global__ __launch_bounds__(256) void k_gemm2(const float* __restrict__ xemb,
                                               const bf16x8* __restrict__ wp2,
                                               const float* __restrict__ dis,
                                               u16* __restrict__ h3b) {
    int tid  = threadIdx.x;
    int lane = tid & 63;
    int wave = tid >> 6;
    int r0   = blockIdx.x * 64 + wave * 16;

    bf16x8 b0 = wp2[lane], b1 = wp2[64 + lane];

    int  arow = r0 + (lane & 15);
    bool aok  = arow < NN;
    const float* xrow = xemb + (size_t)arow * 64 + ((lane >> 4) * 8);

    f32x4 acc = {0,0,0,0};
    #pragma unroll
    for (int kb = 0; kb < 2; ++kb) {
        f32x4 xlo = {0,0,0,0}, xhi = {0,0,0,0};
        if (aok) {
            xlo = *(const f32x4*)(xrow + kb * 32);
            xhi = *(const f32x4*)(xrow + kb * 32 + 4);
        }
        bf16x8 a;
        #pragma unroll
        for (int i = 0; i < 4; ++i) {
            float lo = xlo[i] > 0.f ? xlo[i] : 0.f;   // fused ReLU
            float hi = xhi[i] > 0.f ? xhi[i] : 0.f;
            a[i]     = (__bf16)lo;
            a[i + 4] = (__bf16)hi;
        }
        acc = __builtin_amdgcn_mfma_f32_16x16x32_bf16(a, kb == 0 ? b0 : b1, acc, 0, 0, 0);
    }

    int rbase = r0 + (lane >> 4) * 4;
    int cbase = lane & 15;
    #pragma unroll
    for (int reg = 0; reg < 4; ++reg) {
        int row = rbase + reg;
        if (row < NN)
            h3b[(size_t)row * 16 + cbase] = f2bf(acc[reg] * dis[row]);
    }
}

// ---------------- layer-2 aggregation: wave = node, 16 edges per gather instruction ----------------
__global__ __launch_bounds__(512) void k_agg2(const int2* __restrict__ rowinfo,
                                              const uint2* __restrict__ rec2,
                                              const u16* __restrict__ h3b,
                                              const float* __restrict__ dis,
                                              const float* __restrict__ b2,
                                              float* __restrict__ out) {
    int n    = blockIdx.x * 8 + (threadIdx.x >> 6);
    int lane = threadIdx.x & 63;
    int el   = lane >> 2;        // edge slot 0..15
    int f4   = (lane & 3) * 4;   // feature window (4 bf16 = 8B)
    int2 ri  = rowinfo[n];
    int beg = ri.x, end = ri.y;

    float a0=0,a1=0,a2=0,a3=0;

    u64 p0 = 0, p1 = 0;
    if (beg + el < end)      p0 = nt_load_u64(&rec2[beg + el]);
    if (beg + 16 + el < end) p1 = nt_load_u64(&rec2[beg + 16 + el]);

    for (int j = beg; j < end; j += 32) {
        u64 q0 = 0, q1 = 0;
        if (j + 32 + el < end) q0 = nt_load_u64(&rec2[j + 32 + el]);
        if (j + 48 + el < end) q1 = nt_load_u64(&rec2[j + 48 + el]);
        if (j + el < end) {
            u32 srcn = (u32)(p0 >> 32);
            float nrm = __uint_as_float((u32)p0);
            uint2 hv = *(const uint2*)(h3b + (size_t)srcn * 16 + f4);
            a0 = fmaf(nrm, bfLO(hv.x), a0); a1 = fmaf(nrm, bfHI(hv.x), a1);
            a2 = fmaf(nrm, bfLO(hv.y), a2); a3 = fmaf(nrm, bfHI(hv.y), a3);
        }
        if (j + 16 + el < end) {
            u32 srcn = (u32)(p1 >> 32);
            float nrm = __uint_as_float((u32)p1);
            uint2 hv = *(const uint2*)(h3b + (size_t)srcn * 16 + f4);
            a0 = fmaf(nrm, bfLO(hv.x), a0); a1 = fmaf(nrm, bfHI(hv.x), a1);
            a2 = fmaf(nrm, bfLO(hv.y), a2); a3 = fmaf(nrm, bfHI(hv.y), a3);
        }
        p0 = q0; p1 = q1;
    }

    #pragma unroll
    for (int m = 4; m <= 32; m <<= 1) {
        a0 += __shfl_xor(a0, m, 64);
        a1 += __shfl_xor(a1, m, 64);
        a2 += __shfl_xor(a2, m, 64);
        a3 += __shfl_xor(a3, m, 64);
    }
    if (lane < 4) {
        float di = dis[n];
        uint2 hv = *(const uint2*)(h3b + (size_t)n * 16 + f4);   // self-loop
        float4 bb = *(const float4*)&b2[f4];
        float4 r;
        r.x = fmaf(di, bfLO(hv.x), bb.x) + a0;
        r.y = fmaf(di, bfHI(hv.x), bb.y) + a1;
        r.z = fmaf(di, bfLO(hv.y), bb.z) + a2;
        r.w = fmaf(di, bfHI(hv.y), bb.w) + a3;
        *(float4*)&out[(size_t)n * 16 + f4] = r;
    }
}

extern "C" void kernel_launch(void* const* d_in, const int* in_sizes, int n_in,
                              void* d_out, int out_size, void* d_ws, size_t ws_size,
                              hipStream_t stream) {
    const float* x  = (const float*)d_in[0];
    const int*   ei = (const int*)d_in[1];
    const float* w  = (const float*)d_in[2];
    const float* W1 = (const float*)d_in[3];
    const float* b1 = (const float*)d_in[4];
    const float* W2 = (const float*)d_in[5];
    const float* b2 = (const float*)d_in[6];
    const int* src = ei;
    const int* dst = ei + NE;

    float* out2 = (float*)d_out;               // [NN,16]  output 0
    float* xemb = (float*)d_out + NN * 16;     // [NN,64]  output 1

    // workspace (~33 MB): h1b ALIASES rec_pad (rec dead after k_build)
    uint2*  rec_pad = (uint2*)d_ws;                      // NBKT*CAP uint2 = 16.0MB
    u16*    h1b     = (u16*)d_ws;                        // NN*64 u16 = 12.8MB (alias)
    uint2*  rec2    = rec_pad + (size_t)NBKT * CAP;      // NE uint2 = 12.8MB
    u16*    h3b     = (u16*)(rec2 + NE);                 // NN*16 u16 = 3.2MB
    bf16x8* wp1     = (bf16x8*)(h3b + (size_t)NN * 16);  // 16KB
    bf16x8* wp2     = wp1 + 1024;                        // 2KB
    float*  dis     = (float*)(wp2 + 128);               // NN
    int2*   rowinfo = (int2*)(dis + NN);                 // NN int2
    int*    cursor  = (int*)(rowinfo + NN);              // NBKT
    int*    gctr    = cursor + NBKT;                     // 1

    // --- build (shared by both layers) ---
    k_wpack<<<1,     256, 0, stream>>>(W1, W2, wp1, wp2, cursor, gctr);
    k_part <<<NPB,  1024, 0, stream>>>(src, dst, w, cursor, rec_pad);
    k_build<<<NBKT,  512, 0, stream>>>(cursor, rec_pad, rec2, dis, rowinfo, gctr);

    // --- layer 1 ---
    k_gemm1<<<(NN + 63) / 64, 256, 0, stream>>>(x, wp1, dis, h1b);
    k_agg1 <<<NN / 8, 512, 0, stream>>>(rowinfo, rec2, h1b, dis, b1, xemb);

    // --- layer 2 ---
    k_gemm2<<<(NN + 63) / 64, 256, 0, stream>>>(xemb, wp2, dis, h3b);
    k_agg2 <<<NN / 8, 512, 0, stream>>>(rowinfo, rec2, h3b, dis, b2, out2);
}